// Round 8
// baseline (326.320 us; speedup 1.0000x reference)
//
#include <hip/hip_runtime.h>
#include <cmath>

#define L_SEQ 2048
#define DM 512
#define DI 1024      // D_INNER
#define DS 16        // D_STATE
#define NSP 1056     // DI + 2*DS
#define NC 64        // scan chunks
#define CL 32        // chunk length (NC*CL == L_SEQ)

typedef unsigned short ushortT;
typedef unsigned int u32;
typedef __attribute__((ext_vector_type(8))) short short8;
typedef __attribute__((ext_vector_type(4))) float float4_t;
typedef __attribute__((address_space(1))) u32 gu32;
typedef __attribute__((address_space(3))) u32 lu32;

__device__ __forceinline__ float sigm(float x) { return 1.0f / (1.0f + __expf(-x)); }

__device__ __forceinline__ ushortT f2bf(float f) {
    unsigned u = __float_as_uint(f);
    unsigned r = u + 0x7FFFu + ((u >> 16) & 1u);
    return (ushortT)(r >> 16);
}
__device__ __forceinline__ float b2f(ushortT u) {
    return __uint_as_float(((u32)u) << 16);
}

__device__ __forceinline__ void gl2lds16(const ushortT* g, ushortT* l) {
    __builtin_amdgcn_global_load_lds((gu32*)g, (lu32*)l, 16, 0, 0);
}

// ================= combined preprocessing: weight cvt + x cvt + bias folds ====
struct WC {
    const float* src[11];
    ushortT* dst[11];
    int ss[11], soff[11], ds_[11], tN[11], mode[11];
    int off[12];
};

__global__ __launch_bounds__(256) void prep_all(
    WC wc, int nW,
    const float* __restrict__ x, ushortT* __restrict__ xb,
    const float* __restrict__ xpb0, const float* __restrict__ xpb1,
    const float* __restrict__ dtW0, const float* __restrict__ dtW1,
    const float* __restrict__ dtb0, const float* __restrict__ dtb1,
    const float* __restrict__ outb0, const float* __restrict__ outb1,
    const float* __restrict__ fuW, const float* __restrict__ fub,
    float* __restrict__ BFdt0, float* __restrict__ BFdt1, float* __restrict__ BFof)
{
    __shared__ ushortT t[32][33];
    __shared__ float red[256];
    int b = blockIdx.x;
    int tid = threadIdx.x;
    if (b < nW) {
        int m = 0;
        while (b >= wc.off[m + 1]) ++m;
        int tl = b - wc.off[m];
        int n0 = (tl % wc.tN[m]) * 32;
        int k0 = (tl / wc.tN[m]) * 32;
        const float* W = wc.src[m];
        ushortT* D = wc.dst[m];
        int ss = wc.ss[m], soff = wc.soff[m], ds = wc.ds_[m];
        int tx = tid & 31, ty = tid >> 5;
        if (wc.mode[m] == 1) {
            #pragma unroll
            for (int i = 0; i < 32; i += 8)
                D[(size_t)(k0 + ty + i) * ds + n0 + tx] =
                    f2bf(W[(size_t)(k0 + ty + i) * ss + soff + n0 + tx]);
        } else {
            #pragma unroll
            for (int i = 0; i < 32; i += 8)
                t[ty + i][tx] = f2bf(W[(size_t)(k0 + ty + i) * ss + soff + n0 + tx]);
            __syncthreads();
            #pragma unroll
            for (int i = 0; i < 32; i += 8)
                D[(size_t)(n0 + ty + i) * ds + k0 + tx] = t[tx][ty + i];
        }
        return;
    }
    b -= nW;
    if (b < 1024) {
        int i = (b * 256 + tid) * 4;
        float4_t v = *(const float4_t*)(x + i);
        xb[i + 0] = f2bf(v[0]); xb[i + 1] = f2bf(v[1]);
        xb[i + 2] = f2bf(v[2]); xb[i + 3] = f2bf(v[3]);
        return;
    }
    int o = b - 1024;
    float acc = 0.0f;
    if (o < 2112) {
        int dir = o >= 1056;
        int m = o - dir * 1056;
        const float* xpb = dir ? xpb1 : xpb0;
        float* BF = dir ? BFdt1 : BFdt0;
        if (m >= 1024) {
            if (tid == 0) BF[m] = xpb[m];
            return;
        }
        const float* dtW = dir ? dtW1 : dtW0;
        const float* dtb = dir ? dtb1 : dtb0;
        for (int n = tid; n < 1024; n += 256) acc += xpb[n] * dtW[n * 1024 + m];
        red[tid] = acc;
        __syncthreads();
        for (int s = 128; s > 0; s >>= 1) {
            if (tid < s) red[tid] += red[tid + s];
            __syncthreads();
        }
        if (tid == 0) BF[m] = red[0] + dtb[m];
    } else {
        int n = o - 2112;
        for (int j = tid; j < 1024; j += 256) {
            float ob = (j < 512) ? outb0[j] : outb1[j - 512];
            acc += ob * fuW[(size_t)j * 512 + n];
        }
        red[tid] = acc;
        __syncthreads();
        for (int s = 128; s > 0; s >>= 1) {
            if (tid < s) red[tid] += red[tid + s];
            __syncthreads();
        }
        if (tid == 0) BFof[n] = red[0] + fub[n];
    }
}

// ================= MFMA GEMM core (BK=64, dbuf, XOR bank swizzle) ============
template<int BM, int BN>
__device__ __forceinline__ void gemm_core(
    ushortT* As, ushortT* Bs, int bm, int bn,
    const ushortT* __restrict__ A, int lda, int revA,
    const ushortT* __restrict__ A2, int dualK,
    const ushortT* __restrict__ W,
    const float* __restrict__ bias,
    float* __restrict__ Cf, int ldcf,
    float* __restrict__ Cf2, int ldcf2, int Nsplit,
    ushortT* __restrict__ Cb, int ldcb,
    ushortT* __restrict__ Cb2, int ldcb2,
    int M, int N, int K, int epi)
{
    constexpr int BK = 64;
    constexpr int MI = BM / 32;
    constexpr int NI = BN / 32;
    constexpr int CA = BM / 32;
    constexpr int CB = BN / 32;
    constexpr int ABUF = BM * BK;
    constexpr int BBUF = BN * BK;

    const int tid  = threadIdx.x;
    const int wave = tid >> 6;
    const int lane = tid & 63;
    const int quad = lane >> 4;
    const int r    = lane & 15;
    const int wm   = (wave >> 1) * (BM / 2);
    const int wn   = (wave & 1) * (BN / 2);

    const int lrow = lane >> 3;                     // 0..7
    const int lk   = ((lane & 7) ^ lrow) * 8;       // swizzled source granule

    const ushortT* gA[CA]; const ushortT* gA2[CA]; ushortT* lA[CA];
    #pragma unroll
    for (int c = 0; c < CA; ++c) {
        int row = bm + c * 32 + wave * 8 + lrow;
        int r0 = revA ? (M - 1 - row) : row;
        gA[c] = A + (size_t)r0 * lda + lk;
        gA2[c] = dualK ? (A2 + (size_t)(M - 1 - row) * lda + lk) : gA[c];
        lA[c] = &As[(c * 32 + wave * 8) * BK];
    }
    const ushortT* gB[CB]; ushortT* lB[CB];
    #pragma unroll
    for (int c = 0; c < CB; ++c) {
        int row = bn + c * 32 + wave * 8 + lrow;
        if (row > N - 1) row = N - 1;
        gB[c] = W + (size_t)row * K + lk;
        lB[c] = &Bs[(c * 32 + wave * 8) * BK];
    }

    float4_t acc[MI][NI];
    #pragma unroll
    for (int i = 0; i < MI; ++i)
        #pragma unroll
        for (int j = 0; j < NI; ++j)
            acc[i][j] = (float4_t){0.f, 0.f, 0.f, 0.f};

    const int nsteps = K >> 6;

    auto stage = [&](int step, int buf) {
        int kq = step << 6;
        #pragma unroll
        for (int c = 0; c < CA; ++c) {
            const ushortT* s = (!dualK || kq < 1024) ? gA[c] + kq : gA2[c] + (kq - 1024);
            gl2lds16(s, lA[c] + buf * ABUF);
        }
        #pragma unroll
        for (int c = 0; c < CB; ++c)
            gl2lds16(gB[c] + kq, lB[c] + buf * BBUF);
    };
    auto compute = [&](int buf) {
        #pragma unroll
        for (int kh = 0; kh < 2; ++kh) {
            const int slot = (((kh * 4 + quad) ^ (lane & 7)) * 8);
            short8 af[MI], bf[NI];
            #pragma unroll
            for (int mi = 0; mi < MI; ++mi)
                af[mi] = *(const short8*)&As[buf * ABUF + (wm + mi * 16 + r) * BK + slot];
            #pragma unroll
            for (int ni = 0; ni < NI; ++ni)
                bf[ni] = *(const short8*)&Bs[buf * BBUF + (wn + ni * 16 + r) * BK + slot];
            #pragma unroll
            for (int mi = 0; mi < MI; ++mi)
                #pragma unroll
                for (int ni = 0; ni < NI; ++ni)
                    acc[mi][ni] = __builtin_amdgcn_mfma_f32_16x16x32_bf16(
                        af[mi], bf[ni], acc[mi][ni], 0, 0, 0);
        }
    };

    stage(0, 0);
    for (int i = 0; i < nsteps; i += 2) {
        __syncthreads();
        if (i + 1 < nsteps) stage(i + 1, 1);
        compute(0);
        __syncthreads();
        if (i + 2 < nsteps) stage(i + 2, 0);
        compute(1);
    }

    // epilogue: C/D layout col = lane&15, row = quad*4 + reg
    #pragma unroll
    for (int mi = 0; mi < MI; ++mi) {
        int rowb = bm + wm + mi * 16 + quad * 4;
        #pragma unroll
        for (int ni = 0; ni < NI; ++ni) {
            int gn = bn + wn + ni * 16 + r;
            if (gn < N) {
                float bv = bias ? bias[gn] : 0.0f;
                #pragma unroll
                for (int j = 0; j < 4; ++j) {
                    int orow = rowb + j;
                    float v = acc[mi][ni][j] + bv;
                    if (gn < Nsplit) {
                        if (epi == 1) v = (v > 20.0f) ? v : log1pf(__expf(v));
                        if (Cf) Cf[(size_t)orow * ldcf + gn] = v;
                        if (Cb) Cb[(size_t)orow * ldcb + gn] = f2bf(v);
                    } else {
                        if (Cf2) Cf2[(size_t)orow * ldcf2 + gn - Nsplit] = v;
                        if (Cb2) Cb2[(size_t)orow * ldcb2 + gn - Nsplit] = f2bf(v);
                    }
                }
            }
        }
    }
}

// main GEMM: dirs in blockIdx.z; revAmode 0/2(rev if dir1)/3(dual-K concat)
// swz: 0 none, 1 XCD-cluster (dir, N-quarter), 2 XCD-cluster (dir, M-range)
template<int BM, int BN>
__global__ __launch_bounds__(256) void gemm_bf16(
    const ushortT* __restrict__ A, int lda, long long Astr, int revAmode,
    const ushortT* __restrict__ W, long long Wstr,
    const float* __restrict__ bias0, const float* __restrict__ bias1,
    float* __restrict__ Cf, int ldcf, long long Cfstr,
    float* __restrict__ Cf2, int ldcf2, long long Cf2str, int Nsplit,
    ushortT* __restrict__ Cb, int ldcb, long long Cbstr,
    ushortT* __restrict__ Cb2, int ldcb2, long long Cb2str,
    int swz, int M, int N, int K, int epi)
{
    __shared__ ushortT As[2 * BM * 64];
    __shared__ ushortT Bs[2 * BN * 64];
    int bx = blockIdx.x, by = blockIdx.y, dir = blockIdx.z;
    if (swz) {
        int gx = gridDim.x, gy = gridDim.y, gz = gridDim.z;
        long long b = ((long long)dir * gy + by) * gx + bx;
        int xc = (int)(b & 7);
        long long k = b >> 3;
        if (gz == 2) {
            dir = xc & 1;
            int q = xc >> 1;
            if (swz == 1) { int qc = gx >> 2; bx = q * qc + (int)(k % qc); by = (int)(k / qc); }
            else          { int qc = gy >> 2; by = q * qc + (int)(k % qc); bx = (int)(k / qc); }
        } else {
            if (swz == 1) { int qc = gx >> 3; bx = xc * qc + (int)(k % qc); by = (int)(k / qc); }
            else          { int qc = gy >> 3; by = xc * qc + (int)(k % qc); bx = (int)(k / qc); }
        }
    }
    const ushortT* Ad = A;
    const ushortT* A2 = A;
    int revA = 0, dualK = 0;
    if (revAmode == 3) { dualK = 1; A2 = A + Astr; }
    else { Ad += (size_t)dir * Astr; revA = (revAmode == 2) ? dir : revAmode; }
    gemm_core<BM, BN>(As, Bs, by * BM, bx * BN,
        Ad, lda, revA, A2, dualK,
        W + (size_t)dir * Wstr,
        dir ? bias1 : bias0,
        Cf ? Cf + (size_t)dir * Cfstr : nullptr, ldcf,
        Cf2 ? Cf2 + (size_t)dir * Cf2str : nullptr, ldcf2, Nsplit,
        Cb ? Cb + (size_t)dir * Cbstr : nullptr, ldcb,
        Cb2 ? Cb2 + (size_t)dir * Cb2str : nullptr, ldcb2,
        M, N, K, epi);
}

// both weight folds in one dispatch
__global__ __launch_bounds__(256) void gemm_fold(
    const ushortT* __restrict__ WtDt, const ushortT* __restrict__ XpD,
    ushortT* __restrict__ WtXpF,
    const ushortT* __restrict__ WtFu, const ushortT* __restrict__ OutC,
    ushortT* __restrict__ WtOF2)
{
    __shared__ ushortT As[2 * 64 * 64];
    __shared__ ushortT Bs[2 * 64 * 64];
    int z = blockIdx.z;
    if (z < 2) {
        gemm_core<64, 64>(As, Bs, blockIdx.y * 64, blockIdx.x * 64,
            WtDt + (size_t)z * DI * DI, DI, 0, nullptr, 0,
            XpD + (size_t)z * DI * DI,
            nullptr, nullptr, 0, nullptr, 0, DI,
            WtXpF + (size_t)z * NSP * DI, DI, nullptr, 0,
            DI, DI, DI, 0);
    } else {
        if (blockIdx.y >= 8) return;
        int d = z - 2;
        gemm_core<64, 64>(As, Bs, blockIdx.y * 64, blockIdx.x * 64,
            WtFu + (size_t)d * DM, DI, 0, nullptr, 0,
            OutC + (size_t)d * DI * DM,
            nullptr, nullptr, 0, nullptr, 0, DI,
            WtOF2 + (size_t)d * DI, 2 * DI, nullptr, 0,
            DM, DI, DM, 0);
    }
}

// ---- conv for the xp GEMM input only: SCb = silu(conv(XSb)), both dirs ----
__global__ __launch_bounds__(256) void conv_k(
    const ushortT* __restrict__ XSb,
    const float* __restrict__ cw0, const float* __restrict__ cw1,
    const float* __restrict__ cb0, const float* __restrict__ cb1,
    ushortT* __restrict__ SCb)
{
    int dir = blockIdx.z;
    XSb += (size_t)dir * L_SEQ * DI;
    SCb += (size_t)dir * L_SEQ * DI;
    const float* cw = dir ? cw1 : cw0;
    const float* cb = dir ? cb1 : cb0;
    int idx = blockIdx.x * 256 + threadIdx.x;  // l*DI + d
    int d = idx & (DI - 1);
    int l = idx >> 10;
    float w0 = cw[d * 4 + 0], w1 = cw[d * 4 + 1], w2 = cw[d * 4 + 2], w3 = cw[d * 4 + 3];
    float acc = cb[d];
    if (l >= 3) acc += b2f(XSb[(size_t)(l - 3) * DI + d]) * w0;
    if (l >= 2) acc += b2f(XSb[(size_t)(l - 2) * DI + d]) * w1;
    if (l >= 1) acc += b2f(XSb[(size_t)(l - 1) * DI + d]) * w2;
    acc += b2f(XSb[(size_t)l * DI + d]) * w3;
    SCb[idx] = f2bf(acc * sigm(acc));
}

// ---- Phase A: conv recomputed on the fly (rolling window) ----
__global__ __launch_bounds__(256) void scanA_k(
    const ushortT* __restrict__ DTb, const ushortT* __restrict__ XSb,
    const float* __restrict__ BC, const float* __restrict__ Alog,
    const float* __restrict__ cw0, const float* __restrict__ cw1,
    const float* __restrict__ cb0, const float* __restrict__ cb1,
    float* __restrict__ Pend, float* __restrict__ Hl)
{
    __shared__ float Bsh[CL][DS];
    int dir = blockIdx.z;
    int c = blockIdx.y;
    int d = blockIdx.x * 256 + threadIdx.x;
    DTb += (size_t)dir * L_SEQ * DI;
    XSb += (size_t)dir * L_SEQ * DI;
    BC  += (size_t)dir * L_SEQ * 32;
    const float* cw = dir ? cw1 : cw0;
    const float* cb = dir ? cb1 : cb0;
    int l0 = c * CL;
    for (int i = threadIdx.x; i < CL * DS; i += 256) {
        int ll = i >> 4, ss = i & 15;
        Bsh[ll][ss] = BC[(size_t)(l0 + ll) * 32 + ss];
    }
    __syncthreads();
    float w0 = cw[d * 4 + 0], w1 = cw[d * 4 + 1], w2 = cw[d * 4 + 2], w3 = cw[d * 4 + 3];
    float cbv = cb[d];
    float x3 = (l0 >= 3) ? b2f(XSb[(size_t)(l0 - 3) * DI + d]) : 0.f;
    float x2 = (l0 >= 2) ? b2f(XSb[(size_t)(l0 - 2) * DI + d]) : 0.f;
    float x1 = (l0 >= 1) ? b2f(XSb[(size_t)(l0 - 1) * DI + d]) : 0.f;
    float Ae[DS], h[DS], P[DS];
    #pragma unroll
    for (int s = 0; s < DS; ++s) { Ae[s] = -__expf(Alog[d * DS + s]); h[s] = 0.f; P[s] = 1.f; }
    for (int t = 0; t < CL; ++t) {
        int l = l0 + t;
        float x0 = b2f(XSb[(size_t)l * DI + d]);
        float xv = cbv + w0 * x3 + w1 * x2 + w2 * x1 + w3 * x0;
        x3 = x2; x2 = x1; x1 = x0;
        float dt = b2f(DTb[(size_t)l * DI + d]);
        float dtx = dt * xv;
        #pragma unroll
        for (int s = 0; s < DS; ++s) {
            float e = __expf(dt * Ae[s]);
            h[s] = e * h[s] + dtx * Bsh[t][s];
            P[s] *= e;
        }
    }
    size_t o = ((size_t)(dir * NC + c) * DI + d) * DS;
    #pragma unroll
    for (int s = 0; s < DS; ++s) { Pend[o + s] = P[s]; Hl[o + s] = h[s]; }
}

// ---- Phase B ----
__global__ __launch_bounds__(256) void scanB_k(
    const float* __restrict__ Pend, const float* __restrict__ Hl, float* __restrict__ Hs)
{
    int idx = blockIdx.x * 256 + threadIdx.x;
    float h = 0.f;
    int ds = idx & 16383;
    int dir = idx >> 14;
    for (int c = 0; c < NC; ++c) {
        size_t o = ((size_t)(dir * NC + c)) * (DI * DS) + ds;
        Hs[o] = h;
        h = Pend[o] * h + Hl[o];
    }
}

// ---- Phase C: conv recomputed; fuse y, D-skip, silu(z) gate -> bf16 ----
__global__ __launch_bounds__(256) void scanC_k(
    const ushortT* __restrict__ DTb, const ushortT* __restrict__ XSb,
    const float* __restrict__ BC, const ushortT* __restrict__ Zb,
    const float* __restrict__ Alog, const float* __restrict__ Dp,
    const float* __restrict__ cw0, const float* __restrict__ cw1,
    const float* __restrict__ cb0, const float* __restrict__ cb1,
    const float* __restrict__ Hs, ushortT* __restrict__ Gb)
{
    __shared__ float Bsh[CL][DS];
    __shared__ float Csh[CL][DS];
    int dir = blockIdx.z;
    int c = blockIdx.y;
    int d = blockIdx.x * 256 + threadIdx.x;
    DTb += (size_t)dir * L_SEQ * DI;
    XSb += (size_t)dir * L_SEQ * DI;
    BC  += (size_t)dir * L_SEQ * 32;
    Zb  += (size_t)dir * L_SEQ * DI;
    Gb  += (size_t)dir * L_SEQ * DI;
    const float* cw = dir ? cw1 : cw0;
    const float* cb = dir ? cb1 : cb0;
    int l0 = c * CL;
    for (int i = threadIdx.x; i < CL * DS; i += 256) {
        int ll = i >> 4, ss = i & 15;
        size_t base = (size_t)(l0 + ll) * 32;
        Bsh[ll][ss] = BC[base + ss];
        Csh[ll][ss] = BC[base + DS + ss];
    }
    __syncthreads();
    float w0 = cw[d * 4 + 0], w1 = cw[d * 4 + 1], w2 = cw[d * 4 + 2], w3 = cw[d * 4 + 3];
    float cbv = cb[d];
    float x3 = (l0 >= 3) ? b2f(XSb[(size_t)(l0 - 3) * DI + d]) : 0.f;
    float x2 = (l0 >= 2) ? b2f(XSb[(size_t)(l0 - 2) * DI + d]) : 0.f;
    float x1 = (l0 >= 1) ? b2f(XSb[(size_t)(l0 - 1) * DI + d]) : 0.f;
    float Ae[DS], h[DS];
    size_t o = ((size_t)(dir * NC + c) * DI + d) * DS;
    #pragma unroll
    for (int s = 0; s < DS; ++s) { Ae[s] = -__expf(Alog[d * DS + s]); h[s] = Hs[o + s]; }
    float dpv = Dp[d];
    for (int t = 0; t < CL; ++t) {
        int l = l0 + t;
        float x0 = b2f(XSb[(size_t)l * DI + d]);
        float xv = cbv + w0 * x3 + w1 * x2 + w2 * x1 + w3 * x0;
        x3 = x2; x2 = x1; x1 = x0;
        float dt = b2f(DTb[(size_t)l * DI + d]);
        float dtx = dt * xv;
        float y = 0.f;
        #pragma unroll
        for (int s = 0; s < DS; ++s) {
            float e = __expf(dt * Ae[s]);
            h[s] = e * h[s] + dtx * Bsh[t][s];
            y += h[s] * Csh[t][s];
        }
        y += dpv * xv;
        float z = b2f(Zb[(size_t)l * DI + d]);
        Gb[(size_t)l * DI + d] = f2bf(y * (z * sigm(z)));
    }
}

extern "C" void kernel_launch(void* const* d_in, const int* in_sizes, int n_in,
                              void* d_out, int out_size, void* d_ws, size_t ws_size,
                              hipStream_t stream)
{
    (void)in_sizes; (void)n_in; (void)out_size; (void)ws_size;
    const float* x = (const float*)d_in[0];
    const float* inW[2]  = {(const float*)d_in[1],  (const float*)d_in[11]};
    const float* inb[2]  = {(const float*)d_in[2],  (const float*)d_in[12]};
    const float* cw[2]   = {(const float*)d_in[3],  (const float*)d_in[13]};
    const float* cb[2]   = {(const float*)d_in[4],  (const float*)d_in[14]};
    const float* xpW[2]  = {(const float*)d_in[5],  (const float*)d_in[15]};
    const float* xpb[2]  = {(const float*)d_in[6],  (const float*)d_in[16]};
    const float* dtW[2]  = {(const float*)d_in[7],  (const float*)d_in[17]};
    const float* dtb[2]  = {(const float*)d_in[8],  (const float*)d_in[18]};
    const float* outW[2] = {(const float*)d_in[9],  (const float*)d_in[19]};
    const float* outb[2] = {(const float*)d_in[10], (const float*)d_in[20]};
    const float* Alog = (const float*)d_in[21];
    const float* Dp   = (const float*)d_in[22];
    const float* fuW  = (const float*)d_in[23];
    const float* fub  = (const float*)d_in[24];
    float* out = (float*)d_out;

    float* ws = (float*)d_ws;
    size_t off = 0;
    auto alloc = [&](size_t n) { float* p = ws + off; off += n; return p; };
    float* BCf  = alloc((size_t)2 * L_SEQ * 32);
    float* Pend = alloc((size_t)2 * NC * DI * DS);
    float* Hl   = alloc((size_t)2 * NC * DI * DS);
    float* Hs   = alloc((size_t)2 * NC * DI * DS);
    float* BFdt0 = alloc(1056);
    float* BFdt1 = alloc(1056);
    float* BFof  = alloc(512);

    ushortT* wsu = (ushortT*)(ws + off);
    size_t uoff = 0;
    auto ualloc = [&](size_t n) { ushortT* p = wsu + uoff; uoff += n; return p; };
    ushortT* WtIn  = ualloc((size_t)2 * (2 * DI) * DM);
    ushortT* WtDt  = ualloc((size_t)2 * DI * DI);
    ushortT* WtFu  = ualloc((size_t)DM * DI);
    ushortT* WtXpF = ualloc((size_t)2 * NSP * DI);
    ushortT* XpD   = ualloc((size_t)2 * DI * DI);
    ushortT* OutC  = ualloc((size_t)2 * DI * DM);
    ushortT* WtOF2 = ualloc((size_t)DM * 2 * DI);   // [n][dir*1024 + k]
    ushortT* XB    = ualloc((size_t)L_SEQ * DM);
    ushortT* XSb   = ualloc((size_t)2 * L_SEQ * DI);  // bf16 x_ssm (pre-conv)
    ushortT* Zb    = ualloc((size_t)2 * L_SEQ * DI);  // bf16 z
    ushortT* SCb   = ualloc((size_t)2 * L_SEQ * DI);  // bf16 silu(conv)
    ushortT* DTbB  = ualloc((size_t)2 * L_SEQ * DI);  // bf16 softplus(dt)
    ushortT* Gb    = ualloc((size_t)2 * L_SEQ * DI);

    dim3 blk(256);

    // 0) combined preprocessing
    WC wc;
    struct E { const float* s; ushortT* d; int ss, so, ds, N, K, mode; };
    E es[11] = {
        {inW[0],  WtIn,                          2 * DI, 0,    DM, 2 * DI, DM, 0},
        {inW[1],  WtIn + (size_t)2 * DI * DM,    2 * DI, 0,    DM, 2 * DI, DM, 0},
        {dtW[0],  WtDt,                          DI,     0,    DI, DI,     DI, 0},
        {dtW[1],  WtDt + (size_t)DI * DI,        DI,     0,    DI, DI,     DI, 0},
        {fuW,     WtFu,                          DM,     0,    DI, DM,     DI, 0},
        {xpW[0],  WtXpF + (size_t)DI * DI,       NSP,    DI,   DI, 32,     DI, 0},
        {xpW[1],  WtXpF + (size_t)NSP * DI + (size_t)DI * DI, NSP, DI, DI, 32, DI, 0},
        {xpW[0],  XpD,                           NSP,    0,    DI, DI,     DI, 1},
        {xpW[1],  XpD + (size_t)DI * DI,         NSP,    0,    DI, DI,     DI, 1},
        {outW[0], OutC,                          DM,     0,    DM, DM,     DI, 1},
        {outW[1], OutC + (size_t)DI * DM,        DM,     0,    DM, DM,     DI, 1},
    };
    wc.off[0] = 0;
    for (int m = 0; m < 11; ++m) {
        wc.src[m] = es[m].s; wc.dst[m] = es[m].d;
        wc.ss[m] = es[m].ss; wc.soff[m] = es[m].so; wc.ds_[m] = es[m].ds;
        wc.tN[m] = es[m].N / 32; wc.mode[m] = es[m].mode;
        wc.off[m + 1] = wc.off[m] + (es[m].N / 32) * (es[m].K / 32);
    }
    int nW = wc.off[11];
    prep_all<<<dim3(nW + 1024 + 2624), blk, 0, stream>>>(
        wc, nW, x, XB,
        xpb[0], xpb[1], dtW[0], dtW[1], dtb[0], dtb[1],
        outb[0], outb[1], fuW, fub, BFdt0, BFdt1, BFof);

    // 0b) both weight folds
    gemm_fold<<<dim3(16, 16, 4), blk, 0, stream>>>(WtDt, XpD, WtXpF, WtFu, OutC, WtOF2);

    // 1) input projection -> bf16 XSb | Zb (dir1 reads x reversed); XCD n-cluster
    gemm_bf16<128, 64><<<dim3(32, 16, 2), blk, 0, stream>>>(
        XB, DM, 0, 2, WtIn, (long long)2 * DI * DM, inb[0], inb[1],
        nullptr, 0, 0, nullptr, 0, 0, DI,
        XSb, DI, (long long)L_SEQ * DI, Zb, DI, (long long)L_SEQ * DI,
        1, L_SEQ, 2 * DI, DM, 0);
    // 2) conv + silu -> SCb (xp GEMM input only)
    conv_k<<<dim3(L_SEQ * DI / 256, 1, 2), blk, 0, stream>>>(
        XSb, cw[0], cw[1], cb[0], cb[1], SCb);
    // 3) xp-fused: [softplus(dt)->bf16 | B,C->fp32]; XCD m-cluster
    gemm_bf16<128, 64><<<dim3((NSP + 63) / 64, 16, 2), blk, 0, stream>>>(
        SCb, DI, (long long)L_SEQ * DI, 0, WtXpF, (long long)NSP * DI, BFdt0, BFdt1,
        nullptr, 0, 0, BCf, 32, (long long)L_SEQ * 32, DI,
        DTbB, DI, (long long)L_SEQ * DI, nullptr, 0, 0,
        2, L_SEQ, NSP, DI, 1);
    // 4) chunked selective scan (conv fused via rolling window)
    scanA_k<<<dim3(DI / 256, NC, 2), blk, 0, stream>>>(
        DTbB, XSb, BCf, Alog, cw[0], cw[1], cb[0], cb[1], Pend, Hl);
    scanB_k<<<dim3(2 * DI * DS / 256), blk, 0, stream>>>(Pend, Hl, Hs);
    scanC_k<<<dim3(DI / 256, NC, 2), blk, 0, stream>>>(
        DTbB, XSb, BCf, Zb, Alog, Dp, cw[0], cw[1], cb[0], cb[1], Hs, Gb);
    // 5) fused out-proj + fusion, dual-K concat, single store; XCD m-cluster
    gemm_bf16<64, 64><<<dim3(DM / 64, 32, 1), blk, 0, stream>>>(
        Gb, DI, (long long)L_SEQ * DI, 3, WtOF2, 0, BFof, BFof,
        out, DM, 0, nullptr, 0, 0, DM,
        nullptr, 0, 0, nullptr, 0, 0,
        2, L_SEQ, DM, 2 * DI, 0);
}

// Round 9
// 318.220 us; speedup vs baseline: 1.0255x; 1.0255x over previous
//
#include <hip/hip_runtime.h>
#include <cmath>

#define L_SEQ 2048
#define DM 512
#define DI 1024      // D_INNER
#define DS 16        // D_STATE
#define NSP 1056     // DI + 2*DS
#define NC 64        // scan chunks
#define CL 32        // chunk length (NC*CL == L_SEQ)

typedef unsigned short ushortT;
typedef unsigned int u32;
typedef __attribute__((ext_vector_type(8))) short short8;
typedef __attribute__((ext_vector_type(4))) unsigned short ushort4_t;
typedef __attribute__((ext_vector_type(4))) float float4_t;
typedef __attribute__((address_space(1))) u32 gu32;
typedef __attribute__((address_space(3))) u32 lu32;

__device__ __forceinline__ float sigm(float x) { return 1.0f / (1.0f + __expf(-x)); }

__device__ __forceinline__ ushortT f2bf(float f) {
    unsigned u = __float_as_uint(f);
    unsigned r = u + 0x7FFFu + ((u >> 16) & 1u);
    return (ushortT)(r >> 16);
}
__device__ __forceinline__ float b2f(ushortT u) {
    return __uint_as_float(((u32)u) << 16);
}

__device__ __forceinline__ void gl2lds16(const ushortT* g, ushortT* l) {
    __builtin_amdgcn_global_load_lds((gu32*)g, (lu32*)l, 16, 0, 0);
}

// ================= combined preprocessing: weight cvt + x cvt + bias folds ====
struct WC {
    const float* src[11];
    ushortT* dst[11];
    int ss[11], soff[11], ds_[11], tN[11], mode[11];
    int off[12];
};

__global__ __launch_bounds__(256) void prep_all(
    WC wc, int nW,
    const float* __restrict__ x, ushortT* __restrict__ xb,
    const float* __restrict__ xpb0, const float* __restrict__ xpb1,
    const float* __restrict__ dtW0, const float* __restrict__ dtW1,
    const float* __restrict__ dtb0, const float* __restrict__ dtb1,
    const float* __restrict__ outb0, const float* __restrict__ outb1,
    const float* __restrict__ fuW, const float* __restrict__ fub,
    float* __restrict__ BFdt0, float* __restrict__ BFdt1, float* __restrict__ BFof)
{
    __shared__ ushortT t[32][33];
    __shared__ float red[256];
    int b = blockIdx.x;
    int tid = threadIdx.x;
    if (b < nW) {
        int m = 0;
        while (b >= wc.off[m + 1]) ++m;
        int tl = b - wc.off[m];
        int n0 = (tl % wc.tN[m]) * 32;
        int k0 = (tl / wc.tN[m]) * 32;
        const float* W = wc.src[m];
        ushortT* D = wc.dst[m];
        int ss = wc.ss[m], soff = wc.soff[m], ds = wc.ds_[m];
        int tx = tid & 31, ty = tid >> 5;
        if (wc.mode[m] == 1) {
            #pragma unroll
            for (int i = 0; i < 32; i += 8)
                D[(size_t)(k0 + ty + i) * ds + n0 + tx] =
                    f2bf(W[(size_t)(k0 + ty + i) * ss + soff + n0 + tx]);
        } else {
            #pragma unroll
            for (int i = 0; i < 32; i += 8)
                t[ty + i][tx] = f2bf(W[(size_t)(k0 + ty + i) * ss + soff + n0 + tx]);
            __syncthreads();
            #pragma unroll
            for (int i = 0; i < 32; i += 8)
                D[(size_t)(n0 + ty + i) * ds + k0 + tx] = t[tx][ty + i];
        }
        return;
    }
    b -= nW;
    if (b < 1024) {
        int i = (b * 256 + tid) * 4;
        float4_t v = *(const float4_t*)(x + i);
        xb[i + 0] = f2bf(v[0]); xb[i + 1] = f2bf(v[1]);
        xb[i + 2] = f2bf(v[2]); xb[i + 3] = f2bf(v[3]);
        return;
    }
    int o = b - 1024;
    float acc = 0.0f;
    if (o < 2112) {
        int dir = o >= 1056;
        int m = o - dir * 1056;
        const float* xpb = dir ? xpb1 : xpb0;
        float* BF = dir ? BFdt1 : BFdt0;
        if (m >= 1024) {
            if (tid == 0) BF[m] = xpb[m];
            return;
        }
        const float* dtW = dir ? dtW1 : dtW0;
        const float* dtb = dir ? dtb1 : dtb0;
        for (int n = tid; n < 1024; n += 256) acc += xpb[n] * dtW[n * 1024 + m];
        red[tid] = acc;
        __syncthreads();
        for (int s = 128; s > 0; s >>= 1) {
            if (tid < s) red[tid] += red[tid + s];
            __syncthreads();
        }
        if (tid == 0) BF[m] = red[0] + dtb[m];
    } else {
        int n = o - 2112;
        for (int j = tid; j < 1024; j += 256) {
            float ob = (j < 512) ? outb0[j] : outb1[j - 512];
            acc += ob * fuW[(size_t)j * 512 + n];
        }
        red[tid] = acc;
        __syncthreads();
        for (int s = 128; s > 0; s >>= 1) {
            if (tid < s) red[tid] += red[tid + s];
            __syncthreads();
        }
        if (tid == 0) BFof[n] = red[0] + fub[n];
    }
}

// ================= MFMA GEMM core (BK=64, dbuf, XOR bank swizzle) ============
template<int BM, int BN>
__device__ __forceinline__ void gemm_core(
    ushortT* As, ushortT* Bs, int bm, int bn,
    const ushortT* __restrict__ A, int lda, int revA,
    const ushortT* __restrict__ A2, int dualK,
    const ushortT* __restrict__ W,
    const float* __restrict__ bias,
    float* __restrict__ Cf, int ldcf,
    float* __restrict__ Cf2, int ldcf2, int Nsplit,
    ushortT* __restrict__ Cb, int ldcb,
    ushortT* __restrict__ Cb2, int ldcb2,
    int M, int N, int K, int epi)
{
    constexpr int BK = 64;
    constexpr int MI = BM / 32;
    constexpr int NI = BN / 32;
    constexpr int CA = BM / 32;
    constexpr int CB = BN / 32;
    constexpr int ABUF = BM * BK;
    constexpr int BBUF = BN * BK;

    const int tid  = threadIdx.x;
    const int wave = tid >> 6;
    const int lane = tid & 63;
    const int quad = lane >> 4;
    const int r    = lane & 15;
    const int wm   = (wave >> 1) * (BM / 2);
    const int wn   = (wave & 1) * (BN / 2);

    const int lrow = lane >> 3;                     // 0..7
    const int lk   = ((lane & 7) ^ lrow) * 8;       // swizzled source granule

    const ushortT* gA[CA]; const ushortT* gA2[CA]; ushortT* lA[CA];
    #pragma unroll
    for (int c = 0; c < CA; ++c) {
        int row = bm + c * 32 + wave * 8 + lrow;
        int r0 = revA ? (M - 1 - row) : row;
        gA[c] = A + (size_t)r0 * lda + lk;
        gA2[c] = dualK ? (A2 + (size_t)(M - 1 - row) * lda + lk) : gA[c];
        lA[c] = &As[(c * 32 + wave * 8) * BK];
    }
    const ushortT* gB[CB]; ushortT* lB[CB];
    #pragma unroll
    for (int c = 0; c < CB; ++c) {
        int row = bn + c * 32 + wave * 8 + lrow;
        if (row > N - 1) row = N - 1;
        gB[c] = W + (size_t)row * K + lk;
        lB[c] = &Bs[(c * 32 + wave * 8) * BK];
    }

    float4_t acc[MI][NI];
    #pragma unroll
    for (int i = 0; i < MI; ++i)
        #pragma unroll
        for (int j = 0; j < NI; ++j)
            acc[i][j] = (float4_t){0.f, 0.f, 0.f, 0.f};

    const int nsteps = K >> 6;

    auto stage = [&](int step, int buf) {
        int kq = step << 6;
        #pragma unroll
        for (int c = 0; c < CA; ++c) {
            const ushortT* s = (!dualK || kq < 1024) ? gA[c] + kq : gA2[c] + (kq - 1024);
            gl2lds16(s, lA[c] + buf * ABUF);
        }
        #pragma unroll
        for (int c = 0; c < CB; ++c)
            gl2lds16(gB[c] + kq, lB[c] + buf * BBUF);
    };
    auto compute = [&](int buf) {
        #pragma unroll
        for (int kh = 0; kh < 2; ++kh) {
            const int slot = (((kh * 4 + quad) ^ (lane & 7)) * 8);
            short8 af[MI], bf[NI];
            #pragma unroll
            for (int mi = 0; mi < MI; ++mi)
                af[mi] = *(const short8*)&As[buf * ABUF + (wm + mi * 16 + r) * BK + slot];
            #pragma unroll
            for (int ni = 0; ni < NI; ++ni)
                bf[ni] = *(const short8*)&Bs[buf * BBUF + (wn + ni * 16 + r) * BK + slot];
            #pragma unroll
            for (int mi = 0; mi < MI; ++mi)
                #pragma unroll
                for (int ni = 0; ni < NI; ++ni)
                    acc[mi][ni] = __builtin_amdgcn_mfma_f32_16x16x32_bf16(
                        af[mi], bf[ni], acc[mi][ni], 0, 0, 0);
        }
    };

    stage(0, 0);
    for (int i = 0; i < nsteps; i += 2) {
        __syncthreads();
        if (i + 1 < nsteps) stage(i + 1, 1);
        compute(0);
        __syncthreads();
        if (i + 2 < nsteps) stage(i + 2, 0);
        compute(1);
    }

    // epilogue: C/D layout col = lane&15, row = quad*4 + reg
    #pragma unroll
    for (int mi = 0; mi < MI; ++mi) {
        int rowb = bm + wm + mi * 16 + quad * 4;
        #pragma unroll
        for (int ni = 0; ni < NI; ++ni) {
            int gn = bn + wn + ni * 16 + r;
            if (gn < N) {
                float bv = bias ? bias[gn] : 0.0f;
                #pragma unroll
                for (int j = 0; j < 4; ++j) {
                    int orow = rowb + j;
                    float v = acc[mi][ni][j] + bv;
                    if (gn < Nsplit) {
                        if (epi == 1) v = (v > 20.0f) ? v : log1pf(__expf(v));
                        if (Cf) Cf[(size_t)orow * ldcf + gn] = v;
                        if (Cb) Cb[(size_t)orow * ldcb + gn] = f2bf(v);
                    } else {
                        if (Cf2) Cf2[(size_t)orow * ldcf2 + gn - Nsplit] = v;
                        if (Cb2) Cb2[(size_t)orow * ldcb2 + gn - Nsplit] = f2bf(v);
                    }
                }
            }
        }
    }
}

// ===== mega kernel: in-proj (z<2) + dt-fold (z 2-3) + out-fusion fold (z 4-5) =====
__global__ __launch_bounds__(256) void mega_k(
    const ushortT* __restrict__ XB, const ushortT* __restrict__ WtIn,
    const float* __restrict__ inb0, const float* __restrict__ inb1,
    ushortT* __restrict__ XSb, ushortT* __restrict__ Zb,
    const ushortT* __restrict__ WtDt, const ushortT* __restrict__ XpD,
    ushortT* __restrict__ WtXpF,
    const ushortT* __restrict__ WtFu, const ushortT* __restrict__ OutC,
    ushortT* __restrict__ WtOF2)
{
    __shared__ ushortT As[2 * 128 * 64];
    __shared__ ushortT Bs[2 * 64 * 64];
    int z = blockIdx.z;
    if (z < 2) {
        // in-proj: logical grid x=32 (n-tiles), y=16 (m-tiles), z=2 (dir)
        // XCD cluster: (dir, n-quarter) per XCD
        long long b = ((long long)z * 16 + blockIdx.y) * 32 + blockIdx.x;
        int xc = (int)(b & 7);
        long long k = b >> 3;
        int dir = xc & 1;
        int q = xc >> 1;
        int bx = q * 8 + (int)(k % 8);
        int by = (int)(k / 8);
        gemm_core<128, 64>(As, Bs, by * 128, bx * 64,
            XB, DM, dir, nullptr, 0,
            WtIn + (size_t)dir * 2 * DI * DM,
            dir ? inb1 : inb0,
            nullptr, 0, nullptr, 0, DI,
            XSb + (size_t)dir * L_SEQ * DI, DI,
            Zb + (size_t)dir * L_SEQ * DI, DI,
            L_SEQ, 2 * DI, DM, 0);
    } else if (z < 4) {
        if (blockIdx.x >= 16) return;
        int d = z - 2;
        gemm_core<64, 64>(As, Bs, blockIdx.y * 64, blockIdx.x * 64,
            WtDt + (size_t)d * DI * DI, DI, 0, nullptr, 0,
            XpD + (size_t)d * DI * DI,
            nullptr, nullptr, 0, nullptr, 0, DI,
            WtXpF + (size_t)d * NSP * DI, DI, nullptr, 0,
            DI, DI, DI, 0);
    } else {
        if (blockIdx.x >= 16 || blockIdx.y >= 8) return;
        int d = z - 4;
        gemm_core<64, 64>(As, Bs, blockIdx.y * 64, blockIdx.x * 64,
            WtFu + (size_t)d * DM, DI, 0, nullptr, 0,
            OutC + (size_t)d * DI * DM,
            nullptr, nullptr, 0, nullptr, 0, DI,
            WtOF2 + (size_t)d * DI, 2 * DI, nullptr, 0,
            DM, DI, DM, 0);
    }
}

// main GEMM: dirs in blockIdx.z; revAmode 0/2(rev if dir1)/3(dual-K concat)
// swz: 0 none, 1 XCD-cluster (dir, N-quarter), 2 XCD-cluster (dir, M-range)
template<int BM, int BN>
__global__ __launch_bounds__(256) void gemm_bf16(
    const ushortT* __restrict__ A, int lda, long long Astr, int revAmode,
    const ushortT* __restrict__ W, long long Wstr,
    const float* __restrict__ bias0, const float* __restrict__ bias1,
    float* __restrict__ Cf, int ldcf, long long Cfstr,
    float* __restrict__ Cf2, int ldcf2, long long Cf2str, int Nsplit,
    ushortT* __restrict__ Cb, int ldcb, long long Cbstr,
    ushortT* __restrict__ Cb2, int ldcb2, long long Cb2str,
    int swz, int M, int N, int K, int epi)
{
    __shared__ ushortT As[2 * BM * 64];
    __shared__ ushortT Bs[2 * BN * 64];
    int bx = blockIdx.x, by = blockIdx.y, dir = blockIdx.z;
    if (swz) {
        int gx = gridDim.x, gy = gridDim.y, gz = gridDim.z;
        long long b = ((long long)dir * gy + by) * gx + bx;
        int xc = (int)(b & 7);
        long long k = b >> 3;
        if (gz == 2) {
            dir = xc & 1;
            int q = xc >> 1;
            if (swz == 1) { int qc = gx >> 2; bx = q * qc + (int)(k % qc); by = (int)(k / qc); }
            else          { int qc = gy >> 2; by = q * qc + (int)(k % qc); bx = (int)(k / qc); }
        } else {
            if (swz == 1) { int qc = gx >> 3; bx = xc * qc + (int)(k % qc); by = (int)(k / qc); }
            else          { int qc = gy >> 3; by = xc * qc + (int)(k % qc); bx = (int)(k / qc); }
        }
    }
    const ushortT* Ad = A;
    const ushortT* A2 = A;
    int revA = 0, dualK = 0;
    if (revAmode == 3) { dualK = 1; A2 = A + Astr; }
    else { Ad += (size_t)dir * Astr; revA = (revAmode == 2) ? dir : revAmode; }
    gemm_core<BM, BN>(As, Bs, by * BM, bx * BN,
        Ad, lda, revA, A2, dualK,
        W + (size_t)dir * Wstr,
        dir ? bias1 : bias0,
        Cf ? Cf + (size_t)dir * Cfstr : nullptr, ldcf,
        Cf2 ? Cf2 + (size_t)dir * Cf2str : nullptr, ldcf2, Nsplit,
        Cb ? Cb + (size_t)dir * Cbstr : nullptr, ldcb,
        Cb2 ? Cb2 + (size_t)dir * Cb2str : nullptr, ldcb2,
        M, N, K, epi);
}

// ---- conv for the xp GEMM input: SCb = silu(conv(XSb)), 4 channels/thread ----
__global__ __launch_bounds__(256) void conv_k(
    const ushortT* __restrict__ XSb,
    const float* __restrict__ cw0, const float* __restrict__ cw1,
    const float* __restrict__ cb0, const float* __restrict__ cb1,
    ushortT* __restrict__ SCb)
{
    int dir = blockIdx.z;
    XSb += (size_t)dir * L_SEQ * DI;
    SCb += (size_t)dir * L_SEQ * DI;
    const float* cw = dir ? cw1 : cw0;
    const float* cb = dir ? cb1 : cb0;
    int idx = (blockIdx.x * 256 + threadIdx.x) * 4;   // l*DI + d4
    int d4 = idx & (DI - 1);
    int l = idx >> 10;
    ushort4_t r0 = *(const ushort4_t*)(XSb + (size_t)l * DI + d4);
    ushort4_t r1 = (l >= 1) ? *(const ushort4_t*)(XSb + (size_t)(l - 1) * DI + d4) : (ushort4_t){0,0,0,0};
    ushort4_t r2 = (l >= 2) ? *(const ushort4_t*)(XSb + (size_t)(l - 2) * DI + d4) : (ushort4_t){0,0,0,0};
    ushort4_t r3 = (l >= 3) ? *(const ushort4_t*)(XSb + (size_t)(l - 3) * DI + d4) : (ushort4_t){0,0,0,0};
    ushort4_t outv;
    #pragma unroll
    for (int j = 0; j < 4; ++j) {
        int d = d4 + j;
        float acc = cb[d] + cw[d * 4 + 0] * b2f(r3[j]) + cw[d * 4 + 1] * b2f(r2[j])
                  + cw[d * 4 + 2] * b2f(r1[j]) + cw[d * 4 + 3] * b2f(r0[j]);
        outv[j] = f2bf(acc * sigm(acc));
    }
    *(ushort4_t*)(SCb + idx) = outv;
}

// ---- Phase A: conv recomputed on the fly (rolling window) ----
__global__ __launch_bounds__(256) void scanA_k(
    const ushortT* __restrict__ DTb, const ushortT* __restrict__ XSb,
    const float* __restrict__ BC, const float* __restrict__ Alog,
    const float* __restrict__ cw0, const float* __restrict__ cw1,
    const float* __restrict__ cb0, const float* __restrict__ cb1,
    float* __restrict__ Pend, float* __restrict__ Hl)
{
    __shared__ float Bsh[CL][DS];
    int dir = blockIdx.z;
    int c = blockIdx.y;
    int d = blockIdx.x * 256 + threadIdx.x;
    DTb += (size_t)dir * L_SEQ * DI;
    XSb += (size_t)dir * L_SEQ * DI;
    BC  += (size_t)dir * L_SEQ * 32;
    const float* cw = dir ? cw1 : cw0;
    const float* cb = dir ? cb1 : cb0;
    int l0 = c * CL;
    for (int i = threadIdx.x; i < CL * DS; i += 256) {
        int ll = i >> 4, ss = i & 15;
        Bsh[ll][ss] = BC[(size_t)(l0 + ll) * 32 + ss];
    }
    __syncthreads();
    float w0 = cw[d * 4 + 0], w1 = cw[d * 4 + 1], w2 = cw[d * 4 + 2], w3 = cw[d * 4 + 3];
    float cbv = cb[d];
    float x3 = (l0 >= 3) ? b2f(XSb[(size_t)(l0 - 3) * DI + d]) : 0.f;
    float x2 = (l0 >= 2) ? b2f(XSb[(size_t)(l0 - 2) * DI + d]) : 0.f;
    float x1 = (l0 >= 1) ? b2f(XSb[(size_t)(l0 - 1) * DI + d]) : 0.f;
    float Ae[DS], h[DS], P[DS];
    #pragma unroll
    for (int s = 0; s < DS; ++s) { Ae[s] = -__expf(Alog[d * DS + s]); h[s] = 0.f; P[s] = 1.f; }
    for (int t = 0; t < CL; ++t) {
        int l = l0 + t;
        float x0 = b2f(XSb[(size_t)l * DI + d]);
        float xv = cbv + w0 * x3 + w1 * x2 + w2 * x1 + w3 * x0;
        x3 = x2; x2 = x1; x1 = x0;
        float dt = b2f(DTb[(size_t)l * DI + d]);
        float dtx = dt * xv;
        #pragma unroll
        for (int s = 0; s < DS; ++s) {
            float e = __expf(dt * Ae[s]);
            h[s] = e * h[s] + dtx * Bsh[t][s];
            P[s] *= e;
        }
    }
    size_t o = ((size_t)(dir * NC + c) * DI + d) * DS;
    #pragma unroll
    for (int s = 0; s < DS; ++s) { Pend[o + s] = P[s]; Hl[o + s] = h[s]; }
}

// ---- Phase B ----
__global__ __launch_bounds__(256) void scanB_k(
    const float* __restrict__ Pend, const float* __restrict__ Hl, float* __restrict__ Hs)
{
    int idx = blockIdx.x * 256 + threadIdx.x;
    float h = 0.f;
    int ds = idx & 16383;
    int dir = idx >> 14;
    for (int c = 0; c < NC; ++c) {
        size_t o = ((size_t)(dir * NC + c)) * (DI * DS) + ds;
        Hs[o] = h;
        h = Pend[o] * h + Hl[o];
    }
}

// ---- Phase C: conv recomputed; fuse y, D-skip, silu(z) gate -> bf16 ----
__global__ __launch_bounds__(256) void scanC_k(
    const ushortT* __restrict__ DTb, const ushortT* __restrict__ XSb,
    const float* __restrict__ BC, const ushortT* __restrict__ Zb,
    const float* __restrict__ Alog, const float* __restrict__ Dp,
    const float* __restrict__ cw0, const float* __restrict__ cw1,
    const float* __restrict__ cb0, const float* __restrict__ cb1,
    const float* __restrict__ Hs, ushortT* __restrict__ Gb)
{
    __shared__ float Bsh[CL][DS];
    __shared__ float Csh[CL][DS];
    int dir = blockIdx.z;
    int c = blockIdx.y;
    int d = blockIdx.x * 256 + threadIdx.x;
    DTb += (size_t)dir * L_SEQ * DI;
    XSb += (size_t)dir * L_SEQ * DI;
    BC  += (size_t)dir * L_SEQ * 32;
    Zb  += (size_t)dir * L_SEQ * DI;
    Gb  += (size_t)dir * L_SEQ * DI;
    const float* cw = dir ? cw1 : cw0;
    const float* cb = dir ? cb1 : cb0;
    int l0 = c * CL;
    for (int i = threadIdx.x; i < CL * DS; i += 256) {
        int ll = i >> 4, ss = i & 15;
        size_t base = (size_t)(l0 + ll) * 32;
        Bsh[ll][ss] = BC[base + ss];
        Csh[ll][ss] = BC[base + DS + ss];
    }
    __syncthreads();
    float w0 = cw[d * 4 + 0], w1 = cw[d * 4 + 1], w2 = cw[d * 4 + 2], w3 = cw[d * 4 + 3];
    float cbv = cb[d];
    float x3 = (l0 >= 3) ? b2f(XSb[(size_t)(l0 - 3) * DI + d]) : 0.f;
    float x2 = (l0 >= 2) ? b2f(XSb[(size_t)(l0 - 2) * DI + d]) : 0.f;
    float x1 = (l0 >= 1) ? b2f(XSb[(size_t)(l0 - 1) * DI + d]) : 0.f;
    float Ae[DS], h[DS];
    size_t o = ((size_t)(dir * NC + c) * DI + d) * DS;
    #pragma unroll
    for (int s = 0; s < DS; ++s) { Ae[s] = -__expf(Alog[d * DS + s]); h[s] = Hs[o + s]; }
    float dpv = Dp[d];
    for (int t = 0; t < CL; ++t) {
        int l = l0 + t;
        float x0 = b2f(XSb[(size_t)l * DI + d]);
        float xv = cbv + w0 * x3 + w1 * x2 + w2 * x1 + w3 * x0;
        x3 = x2; x2 = x1; x1 = x0;
        float dt = b2f(DTb[(size_t)l * DI + d]);
        float dtx = dt * xv;
        float y = 0.f;
        #pragma unroll
        for (int s = 0; s < DS; ++s) {
            float e = __expf(dt * Ae[s]);
            h[s] = e * h[s] + dtx * Bsh[t][s];
            y += h[s] * Csh[t][s];
        }
        y += dpv * xv;
        float z = b2f(Zb[(size_t)l * DI + d]);
        Gb[(size_t)l * DI + d] = f2bf(y * (z * sigm(z)));
    }
}

extern "C" void kernel_launch(void* const* d_in, const int* in_sizes, int n_in,
                              void* d_out, int out_size, void* d_ws, size_t ws_size,
                              hipStream_t stream)
{
    (void)in_sizes; (void)n_in; (void)out_size; (void)ws_size;
    const float* x = (const float*)d_in[0];
    const float* inW[2]  = {(const float*)d_in[1],  (const float*)d_in[11]};
    const float* inb[2]  = {(const float*)d_in[2],  (const float*)d_in[12]};
    const float* cw[2]   = {(const float*)d_in[3],  (const float*)d_in[13]};
    const float* cb[2]   = {(const float*)d_in[4],  (const float*)d_in[14]};
    const float* xpW[2]  = {(const float*)d_in[5],  (const float*)d_in[15]};
    const float* xpb[2]  = {(const float*)d_in[6],  (const float*)d_in[16]};
    const float* dtW[2]  = {(const float*)d_in[7],  (const float*)d_in[17]};
    const float* dtb[2]  = {(const float*)d_in[8],  (const float*)d_in[18]};
    const float* outW[2] = {(const float*)d_in[9],  (const float*)d_in[19]};
    const float* outb[2] = {(const float*)d_in[10], (const float*)d_in[20]};
    const float* Alog = (const float*)d_in[21];
    const float* Dp   = (const float*)d_in[22];
    const float* fuW  = (const float*)d_in[23];
    const float* fub  = (const float*)d_in[24];
    float* out = (float*)d_out;

    float* ws = (float*)d_ws;
    size_t off = 0;
    auto alloc = [&](size_t n) { float* p = ws + off; off += n; return p; };
    float* BCf  = alloc((size_t)2 * L_SEQ * 32);
    float* Pend = alloc((size_t)2 * NC * DI * DS);
    float* Hl   = alloc((size_t)2 * NC * DI * DS);
    float* Hs   = alloc((size_t)2 * NC * DI * DS);
    float* BFdt0 = alloc(1056);
    float* BFdt1 = alloc(1056);
    float* BFof  = alloc(512);

    ushortT* wsu = (ushortT*)(ws + off);
    size_t uoff = 0;
    auto ualloc = [&](size_t n) { ushortT* p = wsu + uoff; uoff += n; return p; };
    ushortT* WtIn  = ualloc((size_t)2 * (2 * DI) * DM);
    ushortT* WtDt  = ualloc((size_t)2 * DI * DI);
    ushortT* WtFu  = ualloc((size_t)DM * DI);
    ushortT* WtXpF = ualloc((size_t)2 * NSP * DI);
    ushortT* XpD   = ualloc((size_t)2 * DI * DI);
    ushortT* OutC  = ualloc((size_t)2 * DI * DM);
    ushortT* WtOF2 = ualloc((size_t)DM * 2 * DI);   // [n][dir*1024 + k]
    ushortT* XB    = ualloc((size_t)L_SEQ * DM);
    ushortT* XSb   = ualloc((size_t)2 * L_SEQ * DI);  // bf16 x_ssm (pre-conv)
    ushortT* Zb    = ualloc((size_t)2 * L_SEQ * DI);  // bf16 z
    ushortT* SCb   = ualloc((size_t)2 * L_SEQ * DI);  // bf16 silu(conv)
    ushortT* DTbB  = ualloc((size_t)2 * L_SEQ * DI);  // bf16 softplus(dt)
    ushortT* Gb    = ualloc((size_t)2 * L_SEQ * DI);

    dim3 blk(256);

    // 0) combined preprocessing
    WC wc;
    struct E { const float* s; ushortT* d; int ss, so, ds, N, K, mode; };
    E es[11] = {
        {inW[0],  WtIn,                          2 * DI, 0,    DM, 2 * DI, DM, 0},
        {inW[1],  WtIn + (size_t)2 * DI * DM,    2 * DI, 0,    DM, 2 * DI, DM, 0},
        {dtW[0],  WtDt,                          DI,     0,    DI, DI,     DI, 0},
        {dtW[1],  WtDt + (size_t)DI * DI,        DI,     0,    DI, DI,     DI, 0},
        {fuW,     WtFu,                          DM,     0,    DI, DM,     DI, 0},
        {xpW[0],  WtXpF + (size_t)DI * DI,       NSP,    DI,   DI, 32,     DI, 0},
        {xpW[1],  WtXpF + (size_t)NSP * DI + (size_t)DI * DI, NSP, DI, DI, 32, DI, 0},
        {xpW[0],  XpD,                           NSP,    0,    DI, DI,     DI, 1},
        {xpW[1],  XpD + (size_t)DI * DI,         NSP,    0,    DI, DI,     DI, 1},
        {outW[0], OutC,                          DM,     0,    DM, DM,     DI, 1},
        {outW[1], OutC + (size_t)DI * DM,        DM,     0,    DM, DM,     DI, 1},
    };
    wc.off[0] = 0;
    for (int m = 0; m < 11; ++m) {
        wc.src[m] = es[m].s; wc.dst[m] = es[m].d;
        wc.ss[m] = es[m].ss; wc.soff[m] = es[m].so; wc.ds_[m] = es[m].ds;
        wc.tN[m] = es[m].N / 32; wc.mode[m] = es[m].mode;
        wc.off[m + 1] = wc.off[m] + (es[m].N / 32) * (es[m].K / 32);
    }
    int nW = wc.off[11];
    prep_all<<<dim3(nW + 1024 + 2624), blk, 0, stream>>>(
        wc, nW, x, XB,
        xpb[0], xpb[1], dtW[0], dtW[1], dtb[0], dtb[1],
        outb[0], outb[1], fuW, fub, BFdt0, BFdt1, BFof);

    // 1) mega: in-proj (both dirs) + dt-fold + out-fusion fold, one dispatch
    mega_k<<<dim3(32, 16, 6), blk, 0, stream>>>(
        XB, WtIn, inb[0], inb[1], XSb, Zb,
        WtDt, XpD, WtXpF, WtFu, OutC, WtOF2);

    // 2) conv + silu -> SCb (xp GEMM input only)
    conv_k<<<dim3(L_SEQ * DI / 1024, 1, 2), blk, 0, stream>>>(
        XSb, cw[0], cw[1], cb[0], cb[1], SCb);
    // 3) xp-fused: [softplus(dt)->bf16 | B,C->fp32]; XCD m-cluster
    gemm_bf16<128, 64><<<dim3((NSP + 63) / 64, 16, 2), blk, 0, stream>>>(
        SCb, DI, (long long)L_SEQ * DI, 0, WtXpF, (long long)NSP * DI, BFdt0, BFdt1,
        nullptr, 0, 0, BCf, 32, (long long)L_SEQ * 32, DI,
        DTbB, DI, (long long)L_SEQ * DI, nullptr, 0, 0,
        2, L_SEQ, NSP, DI, 1);
    // 4) chunked selective scan (conv fused via rolling window)
    scanA_k<<<dim3(DI / 256, NC, 2), blk, 0, stream>>>(
        DTbB, XSb, BCf, Alog, cw[0], cw[1], cb[0], cb[1], Pend, Hl);
    scanB_k<<<dim3(2 * DI * DS / 256), blk, 0, stream>>>(Pend, Hl, Hs);
    scanC_k<<<dim3(DI / 256, NC, 2), blk, 0, stream>>>(
        DTbB, XSb, BCf, Zb, Alog, Dp, cw[0], cw[1], cb[0], cb[1], Hs, Gb);
    // 5) fused out-proj + fusion, dual-K concat (K=2048), 64x32 tiles for 2 blocks/CU
    gemm_bf16<64, 32><<<dim3(DM / 32, 32, 1), blk, 0, stream>>>(
        Gb, DI, (long long)L_SEQ * DI, 3, WtOF2, 0, BFof, BFof,
        out, DM, 0, nullptr, 0, 0, DM,
        nullptr, 0, 0, nullptr, 0, 0,
        2, L_SEQ, DM, 2 * DI, 0);
}